// Round 6
// baseline (342.867 us; speedup 1.0000x reference)
//
#include <hip/hip_runtime.h>
#include <hip/hip_bf16.h>
#include <stdint.h>

typedef __hip_bfloat16 bf16;
typedef __attribute__((ext_vector_type(4))) float f32x4;
typedef __attribute__((ext_vector_type(16))) float f32x16;
typedef __attribute__((ext_vector_type(8))) short bf16x8;

#define B_  2
#define S_  2048
#define HID_ 2048
#define NH_ 16
#define NKV_ 2
#define HD_ 128
#define QKV_N 2560           // (NH + 2*NKV) * HD
// SCALE * log2(e): scores in log2 domain so softmax exp is v_exp_f32
#define QSCALE_ (0.08838834764831845f * 1.4426950408889634f)

__device__ __forceinline__ void async_load16(const void* g, void* l) {
    __builtin_amdgcn_global_load_lds(
        (const __attribute__((address_space(1))) unsigned int*)(uintptr_t)g,
        (__attribute__((address_space(3))) unsigned int*)(uintptr_t)l,
        16, 0, 0);
}

__device__ __forceinline__ short f2bf(float f) {
    __hip_bfloat16 h = __float2bfloat16(f);
    return *reinterpret_cast<short*>(&h);
}

// ---------------------------------------------------------------------------
// prep1: fused X cast + Wqkv transpose-cast (phi-permuted) + Wo transpose-cast
// phi swaps bits 5<->6 of the within-head (128) column for Q/K heads so RoPE
// pairs (i, i+64) land in the same lane of the QKV gemm epilogue. Involution.
__global__ void prep1(const float* __restrict__ X, bf16* __restrict__ Xb,
                      const float* __restrict__ Wqkv, bf16* __restrict__ Wqkvt,
                      const float* __restrict__ Wo, bf16* __restrict__ Wot)
{
    __shared__ float t[32][33];
    int bid = blockIdx.x;
    if (bid < 8192) {
        long idx = ((long)bid * 256 + threadIdx.x) * 4;
        float4 v = *(const float4*)(X + idx);
        bf16 o[4];
        o[0] = __float2bfloat16(v.x); o[1] = __float2bfloat16(v.y);
        o[2] = __float2bfloat16(v.z); o[3] = __float2bfloat16(v.w);
        *(ulong1*)(Xb + idx) = *(ulong1*)o;
        return;
    }
    const float* in; bf16* out; int R, C, bx, by; bool perm;
    if (bid < 13312) {
        int v = bid - 8192;          // (80, 64)
        bx = v % 80; by = v / 80;
        in = Wqkv; out = Wqkvt; R = HID_; C = QKV_N; perm = true;
    } else {
        int v = bid - 13312;         // (64, 64)
        bx = v & 63; by = v >> 6;
        in = Wo; out = Wot; R = HID_; C = HID_; perm = false;
    }
    int tx = threadIdx.x & 31, ty = threadIdx.x >> 5;   // 32x8
    int c = bx * 32 + tx;
#pragma unroll
    for (int j = 0; j < 4; j++) {
        int r = by * 32 + ty + j * 8;
        t[ty + j * 8][tx] = in[(long)r * C + c];
    }
    __syncthreads();
#pragma unroll
    for (int j = 0; j < 4; j++) {
        int cc = bx * 32 + ty + j * 8;
        int rr = by * 32 + tx;
        int ccp = cc;
        if (perm && cc < (NH_ + NKV_) * HD_)   // Q/K heads: swap bits 5,6
            ccp = (cc & ~0x60) | ((cc & 0x20) << 1) | ((cc & 0x40) >> 1);
        out[(long)ccp * R + rr] = __float2bfloat16(t[tx][ty + j * 8]);
    }
}

// ---------------------------------------------------------------------------
// QKV GEMM with fused bias + RoPE epilogue. 128x128 tile, BK=64.
// XCD-chunked swizzle (T1): grid 20x32 = 640 = 8*80 blocks.
// V heads write DIRECTLY to VtG[b][j][sigma(s)] (sigma = swap s-bits 2<->3),
// replacing the old Vtmp + v_transpose kernel. sigma on the C-fragment is a
// pure quad-bit swap (reg spans s-bits 0-1, quad spans s-bits 2-3), so each
// lane still emits one 8-byte store per (mi,ni).
__global__ __launch_bounds__(256, 3) void gemm_qkv(
    const bf16* __restrict__ A, const bf16* __restrict__ Bt,
    const float* __restrict__ bias, const int* __restrict__ pos,
    bf16* __restrict__ Qr, bf16* __restrict__ Kr, bf16* __restrict__ VtG)
{
    __shared__ __align__(16) bf16 As[128 * 64];
    __shared__ __align__(16) bf16 Bs[128 * 64];
    const int K = HID_;
    const int tid = threadIdx.x;
    const int wave = tid >> 6, lane = tid & 63;
    const int quad = lane >> 4, l16 = lane & 15;
    const int wr = wave >> 1, wc = wave & 1;

    // T1 XCD swizzle: bijective since nwg % 8 == 0
    const int nwg  = gridDim.x * gridDim.y;
    const int orig = blockIdx.y * gridDim.x + blockIdx.x;
    const int swz  = (orig & 7) * (nwg >> 3) + (orig >> 3);
    const int bx = swz % gridDim.x, by = swz / gridDim.x;

    const long row0 = (long)by * 128;
    const long col0 = (long)bx * 128;

    f32x4 acc[4][4];
#pragma unroll
    for (int i = 0; i < 4; i++)
#pragma unroll
        for (int j = 0; j < 4; j++) acc[i][j] = {0.f, 0.f, 0.f, 0.f};

    for (int k0 = 0; k0 < K; k0 += 64) {
        __syncthreads();
#pragma unroll
        for (int i = 0; i < 4; i++) {
            int cb = i * 256 + wave * 64;
            int c = cb + lane;
            int r = c >> 3, sc = c & 7;
            int gc = sc ^ (r & 7);
            async_load16(A + (row0 + r) * K + k0 + gc * 8, As + (size_t)cb * 8);
            async_load16(Bt + (col0 + r) * K + k0 + gc * 8, Bs + (size_t)cb * 8);
        }
        __syncthreads();

#pragma unroll
        for (int ks2 = 0; ks2 < 2; ks2++) {
            const int slot = ((ks2 * 4 + quad) ^ (l16 & 7)) * 8;
            bf16x8 af[4], bfr[4];
#pragma unroll
            for (int mi = 0; mi < 4; mi++)
                af[mi] = *(const bf16x8*)(As + (wr * 64 + mi * 16 + l16) * 64 + slot);
#pragma unroll
            for (int ni = 0; ni < 4; ni++)
                bfr[ni] = *(const bf16x8*)(Bs + (wc * 64 + ni * 16 + l16) * 64 + slot);
#pragma unroll
            for (int mi = 0; mi < 4; mi++)
#pragma unroll
                for (int ni = 0; ni < 4; ni++)
                    acc[mi][ni] = __builtin_amdgcn_mfma_f32_16x16x32_bf16(
                        af[mi], bfr[ni], acc[mi][ni], 0, 0, 0);
        }
    }

    const int ct = bx;
    if (ct < NH_ + NKV_) {
        // RoPE heads (Q or K)
        const bool isQ = (ct < NH_);
        float invf[2];
#pragma unroll
        for (int np = 0; np < 2; np++) {
            int i = wc * 32 + np * 16 + l16;
            invf[np] = __expf(-(float)i * (13.815510557964274f / 64.0f));
        }
#pragma unroll
        for (int mi = 0; mi < 4; mi++) {
            long r0 = row0 + wr * 64 + mi * 16 + quad * 4;
#pragma unroll
            for (int reg = 0; reg < 4; reg++) {
                long rr = r0 + reg;
                int b = (int)(rr >> 11), s = (int)(rr & 2047);
                float p = (float)pos[rr];
#pragma unroll
                for (int np = 0; np < 2; np++) {
                    int i = wc * 32 + np * 16 + l16;
                    float x1 = acc[mi][np][reg]     + bias[ct * 128 + i];
                    float x2 = acc[mi][np + 2][reg] + bias[ct * 128 + i + 64];
                    float sn, cs;
                    __sincosf(p * invf[np], &sn, &cs);
                    float o1 = x1 * cs - x2 * sn;
                    float o2 = x2 * cs + x1 * sn;
                    if (isQ) {
                        long ob = (((long)b * NH_ + ct) * S_ + s) * HD_;
                        Qr[ob + i]      = __float2bfloat16(o1 * QSCALE_);
                        Qr[ob + i + 64] = __float2bfloat16(o2 * QSCALE_);
                    } else {
                        long ob = (((long)b * NKV_ + (ct - NH_)) * S_ + s) * HD_;
                        Kr[ob + i]      = __float2bfloat16(o1);
                        Kr[ob + i + 64] = __float2bfloat16(o2);
                    }
                }
            }
        }
    } else {
        // V heads: bias + direct sigma-transposed store to VtG[b][j][sigma(s)]
        // quad (s-bits 2-3) bit0<->bit1 swapped; reg = s-bits 0-1 stay packed.
        const int qswap = ((quad & 1) << 1) | ((quad >> 1) & 1);
#pragma unroll
        for (int mi = 0; mi < 4; mi++) {
            long rbase = row0 + wr * 64 + mi * 16;    // 16-aligned
            int bb  = (int)(rbase >> 11);
            int s16 = (int)(rbase & 2047);
#pragma unroll
            for (int ni = 0; ni < 4; ni++) {
                int c = wc * 64 + ni * 16 + l16;
                int j = (ct - 18) * 128 + c;
                float bv = bias[ct * 128 + c];
                bf16 o[4];
#pragma unroll
                for (int reg = 0; reg < 4; reg++)
                    o[reg] = __float2bfloat16(acc[mi][ni][reg] + bv);
                *(ulong1*)(VtG + ((long)(bb * 256 + j)) * S_ + s16 + qswap * 4) =
                    *(ulong1*)o;
            }
        }
    }
}

// ---------------------------------------------------------------------------
// Output projection GEMM: 128x128 tile, BK=64, fp32 out. T1 swizzle (512=8*64).
__global__ __launch_bounds__(256, 3) void gemm_out(
    const bf16* __restrict__ A, const bf16* __restrict__ Bt,
    float* __restrict__ Cout, int M, int N, int K)
{
    __shared__ __align__(16) bf16 As[128 * 64];
    __shared__ __align__(16) bf16 Bs[128 * 64];
    const int tid = threadIdx.x;
    const int wave = tid >> 6, lane = tid & 63;
    const int quad = lane >> 4, l16 = lane & 15;
    const int wr = wave >> 1, wc = wave & 1;

    // T1 XCD swizzle: bijective since nwg % 8 == 0
    const int nwg  = gridDim.x * gridDim.y;
    const int orig = blockIdx.y * gridDim.x + blockIdx.x;
    const int swz  = (orig & 7) * (nwg >> 3) + (orig >> 3);
    const int bx = swz % gridDim.x, by = swz / gridDim.x;

    const long row0 = (long)by * 128;
    const long col0 = (long)bx * 128;

    f32x4 acc[4][4];
#pragma unroll
    for (int i = 0; i < 4; i++)
#pragma unroll
        for (int j = 0; j < 4; j++) acc[i][j] = {0.f, 0.f, 0.f, 0.f};

    for (int k0 = 0; k0 < K; k0 += 64) {
        __syncthreads();
#pragma unroll
        for (int i = 0; i < 4; i++) {
            int cb = i * 256 + wave * 64;
            int c = cb + lane;
            int r = c >> 3, sc = c & 7;
            int gc = sc ^ (r & 7);
            async_load16(A + (row0 + r) * K + k0 + gc * 8, As + (size_t)cb * 8);
            async_load16(Bt + (col0 + r) * K + k0 + gc * 8, Bs + (size_t)cb * 8);
        }
        __syncthreads();

#pragma unroll
        for (int ks2 = 0; ks2 < 2; ks2++) {
            const int slot = ((ks2 * 4 + quad) ^ (l16 & 7)) * 8;
            bf16x8 af[4], bfr[4];
#pragma unroll
            for (int mi = 0; mi < 4; mi++)
                af[mi] = *(const bf16x8*)(As + (wr * 64 + mi * 16 + l16) * 64 + slot);
#pragma unroll
            for (int ni = 0; ni < 4; ni++)
                bfr[ni] = *(const bf16x8*)(Bs + (wc * 64 + ni * 16 + l16) * 64 + slot);
#pragma unroll
            for (int mi = 0; mi < 4; mi++)
#pragma unroll
                for (int ni = 0; ni < 4; ni++)
                    acc[mi][ni] = __builtin_amdgcn_mfma_f32_16x16x32_bf16(
                        af[mi], bfr[ni], acc[mi][ni], 0, 0, 0);
        }
    }

#pragma unroll
    for (int mi = 0; mi < 4; mi++) {
        long r = row0 + wr * 64 + mi * 16 + quad * 4;
#pragma unroll
        for (int ni = 0; ni < 4; ni++) {
            long c = col0 + wc * 64 + ni * 16 + l16;
#pragma unroll
            for (int reg = 0; reg < 4; reg++)
                Cout[(r + reg) * N + c] = acc[mi][ni][reg];
        }
    }
}

// ---------------------------------------------------------------------------
// Causal GQA flash attention, 32x32x16 MFMA, 128q x 64k tiles, 4 waves.
// Round-6: LDS 64KB -> 48KB (K double-buffered 2x16KB, V SINGLE-buffered
// 16KB) + __launch_bounds__(256,3) -> 3 blocks/CU (12 waves/CU, was 8).
// V(kt+1) is staged after a second barrier that closes PV(kt); its
// completion is covered by the next top-of-loop barrier drain. Keeps the
// round-5 fused dual-subtile compute (ILP=2 QK chains, mask specialization).
__global__ __launch_bounds__(256, 3) void attn_kernel(
    const bf16* __restrict__ Q,   // [B][NH][S][HD], pre-scaled by SCALE*log2e
    const bf16* __restrict__ Kk,  // [B][NKV][S][HD]
    const bf16* __restrict__ Vt,  // [B][NKV*HD][sigma(S)]
    bf16* __restrict__ O)         // [B][S][NH*HD]
{
    const int id = blockIdx.x;
    const int hb = id & 31;
    const int h = hb & 15, b = hb >> 4;
    const int q4 = (id >> 5) & 7, hi = id >> 8;
    const int qtile = hi ? (15 - q4) : q4;    // co-resident pair sums to 15
    const int kvh = h >> 3;
    const int tid = threadIdx.x, wave = tid >> 6, lane = tid & 63;
    const int l31 = lane & 31, half = lane >> 5;
    const int qh = wave;                      // q rows qh*32..+31

    __shared__ __align__(16) char smem[48 * 1024];   // K0|K1|V
    __shared__ float Ls[128];

    const bf16* Kbase = Kk + ((long)(b * NKV_ + kvh) * S_) * HD_;
    const bf16* Vbase = Vt + ((long)b * (2 * HD_) + kvh * HD_) * (long)S_;

    // stage all 128 Q rows (32 KB over K0+K1 regions), hoist B-frags
    const bf16* Qg = Q + (((long)(b * NH_ + h) * S_) + qtile * 128) * HD_;
    bf16* Qs = (bf16*)smem;
#pragma unroll
    for (int i = 0; i < 8; i++) {
        int cb = i * 256 + wave * 64;
        int c = cb + lane, r = c >> 4, sc = c & 15;
        async_load16(Qg + r * HD_ + (sc ^ (r & 15)) * 8, Qs + (size_t)cb * 8);
    }
    __syncthreads();
    bf16x8 qf[8];
#pragma unroll
    for (int ks = 0; ks < 8; ks++) {
        int gc = 2 * ks + half;
        qf[ks] = *(const bf16x8*)(Qs + (qh * 32 + l31) * 128 +
                                  ((gc ^ (l31 & 15)) * 8));
    }
    __syncthreads();   // smem now reusable for K/V tiles

    f32x16 acc_o[4];
#pragma unroll
    for (int r = 0; r < 16; r++) {
        acc_o[0][r] = 0.f; acc_o[1][r] = 0.f;
        acc_o[2][r] = 0.f; acc_o[3][r] = 0.f;
    }
    float lsum0 = 0.f, lsum1 = 0.f;

    const int qc32 = qtile * 4 + qh;          // this wave's 32-q chunk index
    const int kt_max = 2 * qtile + 1;

    // prologue: K(0) -> Kbuf[0], V(0) -> Vbuf
    {
        bf16* KsW  = (bf16*)smem;
        bf16* VtsW = (bf16*)(smem + 32768);
#pragma unroll
        for (int i = 0; i < 4; i++) {
            int cb = i * 256 + wave * 64;
            int c = cb + lane, r = c >> 4, sc = c & 15;
            async_load16(Kbase + r * HD_ + (sc ^ (r & 15)) * 8,
                         KsW + (size_t)cb * 8);
        }
#pragma unroll
        for (int i = 0; i < 4; i++) {
            int cb = i * 256 + wave * 64;
            int c = cb + lane, r = c >> 3, sc = c & 7;
            async_load16(Vbase + (long)r * S_ + (sc ^ (r & 7)) * 8,
                         VtsW + (size_t)cb * 8);
        }
    }

#pragma unroll 1
    for (int kt = 0; kt <= kt_max; kt++) {
        __syncthreads();   // drain: K(kt) in Kbuf[kt&1], V(kt) in Vbuf ready
        const bf16* Ks  = (const bf16*)(smem + (kt & 1) * 16384);
        const bf16* Vts = (const bf16*)(smem + 32768);

        if (kt < kt_max) {   // prefetch K(kt+1) into the other K buffer
            bf16* KsW = (bf16*)(smem + ((kt + 1) & 1) * 16384);
            const bf16* Kg = Kbase + (long)(kt + 1) * 64 * HD_;
#pragma unroll
            for (int i = 0; i < 4; i++) {
                int cb = i * 256 + wave * 64;
                int c = cb + lane, r = c >> 4, sc = c & 15;
                async_load16(Kg + r * HD_ + (sc ^ (r & 15)) * 8,
                             KsW + (size_t)cb * 8);
            }
        }

        // --- fused dual-subtile compute -----------------------------------
        auto qk = [&](int mh, f32x16& st) {
#pragma unroll
            for (int ks = 0; ks < 8; ks++) {
                int gc = 2 * ks + half;
                bf16x8 ka = *(const bf16x8*)(Ks + (mh * 32 + l31) * 128 +
                                             ((gc ^ (l31 & 15)) * 8));
                st = __builtin_amdgcn_mfma_f32_32x32x16_bf16(ka, qf[ks], st,
                                                             0, 0, 0);
            }
        };
        auto smax = [&](const f32x16& st, bool tri, bf16x8 (&pa)[2],
                        float& ls) {
#pragma unroll
            for (int t = 0; t < 2; t++)
#pragma unroll
                for (int j = 0; j < 8; j++) {
                    int r = t * 8 + j;
                    int krow = (r & 3) + 8 * (r >> 2) + 4 * half;
                    float x = st[r];
                    if (tri && krow > l31) x = -1e30f;
                    float pv = __builtin_amdgcn_exp2f(x);
                    ls += pv;                 // lane l31 = q here
                    pa[t][j] = f2bf(pv);
                }
        };
        auto pv_acc = [&](int mh, bf16x8 (&pa)[2]) {
#pragma unroll
            for (int t = 0; t < 2; t++) {
                int gc = 4 * mh + 2 * t + half;
#pragma unroll
                for (int nt = 0; nt < 4; nt++) {
                    bf16x8 vb = *(const bf16x8*)(Vts + (nt * 32 + l31) * 64 +
                                                 ((gc ^ (l31 & 7)) * 8));
                    acc_o[nt] = __builtin_amdgcn_mfma_f32_32x32x16_bf16(
                        pa[t], vb, acc_o[nt], 0, 0, 0);
                }
            }
        };

        const int kc0 = 2 * kt, kc1 = 2 * kt + 1;
        if (kc1 <= qc32) {
            // both subtiles live; subtile0 provably unmasked (kc0 < qc32)
            f32x16 st0, st1;
#pragma unroll
            for (int r = 0; r < 16; r++) { st0[r] = 0.f; st1[r] = 0.f; }
            qk(0, st0);
            qk(1, st1);
            bf16x8 pa0[2], pa1[2];
            smax(st0, false, pa0, lsum0);
            smax(st1, kc1 == qc32, pa1, lsum1);
            pv_acc(0, pa0);
            pv_acc(1, pa1);
        } else if (kc0 <= qc32) {
            // single subtile; provably triangular (kc0 == qc32)
            f32x16 st0;
#pragma unroll
            for (int r = 0; r < 16; r++) st0[r] = 0.f;
            qk(0, st0);
            bf16x8 pa0[2];
            smax(st0, true, pa0, lsum0);
            pv_acc(0, pa0);
        }

        if (kt < kt_max) {
            __syncthreads();   // all PV(kt) complete -> Vbuf reusable
            bf16* VtsW = (bf16*)(smem + 32768);
            const bf16* Vg = Vbase + (kt + 1) * 64;
#pragma unroll
            for (int i = 0; i < 4; i++) {
                int cb = i * 256 + wave * 64;
                int c = cb + lane, r = c >> 3, sc = c & 7;
                async_load16(Vg + (long)r * S_ + (sc ^ (r & 7)) * 8,
                             VtsW + (size_t)cb * 8);
            }
        }
    }

    // row-sum broadcast: lsum indexed by lane=q; acc_o rows are reg-indexed q.
    float lsum = lsum0 + lsum1;
    float ltot = lsum + __shfl_xor(lsum, 32);
    __syncthreads();   // all compute done before Ls write
    if (half == 0) Ls[qh * 32 + l31] = ltot;
    __syncthreads();

    float inv_l[16];
#pragma unroll
    for (int r = 0; r < 16; r++) {
        int qrow = (r & 3) + 8 * (r >> 2) + 4 * half;
        inv_l[r] = __builtin_amdgcn_rcpf(Ls[qh * 32 + qrow]);
    }
#pragma unroll
    for (int nt = 0; nt < 4; nt++)
#pragma unroll
        for (int r = 0; r < 16; r++) {
            int qrow = (r & 3) + 8 * (r >> 2) + 4 * half;
            float v = acc_o[nt][r] * inv_l[r];
            O[((long)b * S_ + qtile * 128 + qh * 32 + qrow) * (NH_ * HD_) +
              h * HD_ + nt * 32 + l31] = __float2bfloat16(v);
        }
}

// ---------------------------------------------------------------------------
extern "C" void kernel_launch(void* const* d_in, const int* in_sizes, int n_in,
                              void* d_out, int out_size, void* d_ws, size_t ws_size,
                              hipStream_t stream) {
    const int*   pos  = (const int*)d_in[0];
    const float* X    = (const float*)d_in[1];
    const float* Wqkv = (const float*)d_in[2];
    const float* bqkv = (const float*)d_in[3];
    const float* Wo   = (const float*)d_in[4];
    float* out = (float*)d_out;

    char* ws = (char*)d_ws;
    bf16* Xb    = (bf16*)ws;  ws += (size_t)B_ * S_ * HID_ * 2;
    bf16* Wqkvt = (bf16*)ws;  ws += (size_t)QKV_N * HID_ * 2;
    bf16* Wot   = (bf16*)ws;  ws += (size_t)HID_ * HID_ * 2;
    bf16* Qr    = (bf16*)ws;  ws += (size_t)B_ * NH_ * S_ * HD_ * 2;
    bf16* Kr    = (bf16*)ws;  ws += (size_t)B_ * NKV_ * S_ * HD_ * 2;
    bf16* VtG   = (bf16*)ws;  ws += (size_t)B_ * NKV_ * HD_ * S_ * 2;
    bf16* AO    = (bf16*)ws;  ws += (size_t)B_ * S_ * NH_ * HD_ * 2;

    // 1. fused cast + weight transposes (Wqkvt phi-permuted)
    prep1<<<17408, 256, 0, stream>>>(X, Xb, Wqkv, Wqkvt, Wo, Wot);

    // 2. QKV projection + bias + RoPE + direct sigma'd V write (T1 swizzle)
    gemm_qkv<<<dim3(QKV_N / 128, (B_ * S_) / 128), 256, 0, stream>>>(
        Xb, Wqkvt, bqkv, pos, Qr, Kr, VtG);

    // 3. causal GQA attention (512 blocks, 3 blocks/CU, 48KB LDS)
    attn_kernel<<<dim3(512), 256, 0, stream>>>(Qr, Kr, VtG, AO);

    // 4. output projection (512 blocks, T1 swizzle, fp32 out)
    gemm_out<<<dim3(HID_ / 128, (B_ * S_) / 128), 256, 0, stream>>>(
        AO, Wot, out, B_ * S_, HID_, HID_);
}

// Round 7
// 258.611 us; speedup vs baseline: 1.3258x; 1.3258x over previous
//
#include <hip/hip_runtime.h>
#include <hip/hip_bf16.h>
#include <stdint.h>

typedef __hip_bfloat16 bf16;
typedef __attribute__((ext_vector_type(4))) float f32x4;
typedef __attribute__((ext_vector_type(16))) float f32x16;
typedef __attribute__((ext_vector_type(8))) short bf16x8;

#define B_  2
#define S_  2048
#define HID_ 2048
#define NH_ 16
#define NKV_ 2
#define HD_ 128
#define QKV_N 2560           // (NH + 2*NKV) * HD
// SCALE * log2(e): scores in log2 domain so softmax exp is v_exp_f32
#define QSCALE_ (0.08838834764831845f * 1.4426950408889634f)

__device__ __forceinline__ void async_load16(const void* g, void* l) {
    __builtin_amdgcn_global_load_lds(
        (const __attribute__((address_space(1))) unsigned int*)(uintptr_t)g,
        (__attribute__((address_space(3))) unsigned int*)(uintptr_t)l,
        16, 0, 0);
}

__device__ __forceinline__ short f2bf(float f) {
    __hip_bfloat16 h = __float2bfloat16(f);
    return *reinterpret_cast<short*>(&h);
}

// ---------------------------------------------------------------------------
// prep1: fused X cast + Wqkv transpose-cast (phi-permuted) + Wo transpose-cast
// phi swaps bits 5<->6 of the within-head (128) column for Q/K heads so RoPE
// pairs (i, i+64) land in the same lane of the QKV gemm epilogue. Involution.
__global__ void prep1(const float* __restrict__ X, bf16* __restrict__ Xb,
                      const float* __restrict__ Wqkv, bf16* __restrict__ Wqkvt,
                      const float* __restrict__ Wo, bf16* __restrict__ Wot)
{
    __shared__ float t[32][33];
    int bid = blockIdx.x;
    if (bid < 8192) {
        long idx = ((long)bid * 256 + threadIdx.x) * 4;
        float4 v = *(const float4*)(X + idx);
        bf16 o[4];
        o[0] = __float2bfloat16(v.x); o[1] = __float2bfloat16(v.y);
        o[2] = __float2bfloat16(v.z); o[3] = __float2bfloat16(v.w);
        *(ulong1*)(Xb + idx) = *(ulong1*)o;
        return;
    }
    const float* in; bf16* out; int R, C, bx, by; bool perm;
    if (bid < 13312) {
        int v = bid - 8192;          // (80, 64)
        bx = v % 80; by = v / 80;
        in = Wqkv; out = Wqkvt; R = HID_; C = QKV_N; perm = true;
    } else {
        int v = bid - 13312;         // (64, 64)
        bx = v & 63; by = v >> 6;
        in = Wo; out = Wot; R = HID_; C = HID_; perm = false;
    }
    int tx = threadIdx.x & 31, ty = threadIdx.x >> 5;   // 32x8
    int c = bx * 32 + tx;
#pragma unroll
    for (int j = 0; j < 4; j++) {
        int r = by * 32 + ty + j * 8;
        t[ty + j * 8][tx] = in[(long)r * C + c];
    }
    __syncthreads();
#pragma unroll
    for (int j = 0; j < 4; j++) {
        int cc = bx * 32 + ty + j * 8;
        int rr = by * 32 + tx;
        int ccp = cc;
        if (perm && cc < (NH_ + NKV_) * HD_)   // Q/K heads: swap bits 5,6
            ccp = (cc & ~0x60) | ((cc & 0x20) << 1) | ((cc & 0x40) >> 1);
        out[(long)ccp * R + rr] = __float2bfloat16(t[tx][ty + j * 8]);
    }
}

// ---------------------------------------------------------------------------
// QKV GEMM with fused bias + RoPE epilogue. 128x128 tile, BK=64.
// XCD-chunked swizzle (T1): grid 20x32 = 640 = 8*80 blocks.
// V heads write DIRECTLY to VtG[b][j][sigma(s)] (sigma = swap s-bits 2<->3);
// sigma on the C-fragment is a pure quad-bit swap (reg spans s-bits 0-1,
// quad spans s-bits 2-3), so each lane emits one 8-byte store per (mi,ni).
__global__ __launch_bounds__(256, 3) void gemm_qkv(
    const bf16* __restrict__ A, const bf16* __restrict__ Bt,
    const float* __restrict__ bias, const int* __restrict__ pos,
    bf16* __restrict__ Qr, bf16* __restrict__ Kr, bf16* __restrict__ VtG)
{
    __shared__ __align__(16) bf16 As[128 * 64];
    __shared__ __align__(16) bf16 Bs[128 * 64];
    const int K = HID_;
    const int tid = threadIdx.x;
    const int wave = tid >> 6, lane = tid & 63;
    const int quad = lane >> 4, l16 = lane & 15;
    const int wr = wave >> 1, wc = wave & 1;

    // T1 XCD swizzle: bijective since nwg % 8 == 0
    const int nwg  = gridDim.x * gridDim.y;
    const int orig = blockIdx.y * gridDim.x + blockIdx.x;
    const int swz  = (orig & 7) * (nwg >> 3) + (orig >> 3);
    const int bx = swz % gridDim.x, by = swz / gridDim.x;

    const long row0 = (long)by * 128;
    const long col0 = (long)bx * 128;

    f32x4 acc[4][4];
#pragma unroll
    for (int i = 0; i < 4; i++)
#pragma unroll
        for (int j = 0; j < 4; j++) acc[i][j] = {0.f, 0.f, 0.f, 0.f};

    for (int k0 = 0; k0 < K; k0 += 64) {
        __syncthreads();
#pragma unroll
        for (int i = 0; i < 4; i++) {
            int cb = i * 256 + wave * 64;
            int c = cb + lane;
            int r = c >> 3, sc = c & 7;
            int gc = sc ^ (r & 7);
            async_load16(A + (row0 + r) * K + k0 + gc * 8, As + (size_t)cb * 8);
            async_load16(Bt + (col0 + r) * K + k0 + gc * 8, Bs + (size_t)cb * 8);
        }
        __syncthreads();

#pragma unroll
        for (int ks2 = 0; ks2 < 2; ks2++) {
            const int slot = ((ks2 * 4 + quad) ^ (l16 & 7)) * 8;
            bf16x8 af[4], bfr[4];
#pragma unroll
            for (int mi = 0; mi < 4; mi++)
                af[mi] = *(const bf16x8*)(As + (wr * 64 + mi * 16 + l16) * 64 + slot);
#pragma unroll
            for (int ni = 0; ni < 4; ni++)
                bfr[ni] = *(const bf16x8*)(Bs + (wc * 64 + ni * 16 + l16) * 64 + slot);
#pragma unroll
            for (int mi = 0; mi < 4; mi++)
#pragma unroll
                for (int ni = 0; ni < 4; ni++)
                    acc[mi][ni] = __builtin_amdgcn_mfma_f32_16x16x32_bf16(
                        af[mi], bfr[ni], acc[mi][ni], 0, 0, 0);
        }
    }

    const int ct = bx;
    if (ct < NH_ + NKV_) {
        // RoPE heads (Q or K)
        const bool isQ = (ct < NH_);
        float invf[2];
#pragma unroll
        for (int np = 0; np < 2; np++) {
            int i = wc * 32 + np * 16 + l16;
            invf[np] = __expf(-(float)i * (13.815510557964274f / 64.0f));
        }
#pragma unroll
        for (int mi = 0; mi < 4; mi++) {
            long r0 = row0 + wr * 64 + mi * 16 + quad * 4;
#pragma unroll
            for (int reg = 0; reg < 4; reg++) {
                long rr = r0 + reg;
                int b = (int)(rr >> 11), s = (int)(rr & 2047);
                float p = (float)pos[rr];
#pragma unroll
                for (int np = 0; np < 2; np++) {
                    int i = wc * 32 + np * 16 + l16;
                    float x1 = acc[mi][np][reg]     + bias[ct * 128 + i];
                    float x2 = acc[mi][np + 2][reg] + bias[ct * 128 + i + 64];
                    float sn, cs;
                    __sincosf(p * invf[np], &sn, &cs);
                    float o1 = x1 * cs - x2 * sn;
                    float o2 = x2 * cs + x1 * sn;
                    if (isQ) {
                        long ob = (((long)b * NH_ + ct) * S_ + s) * HD_;
                        Qr[ob + i]      = __float2bfloat16(o1 * QSCALE_);
                        Qr[ob + i + 64] = __float2bfloat16(o2 * QSCALE_);
                    } else {
                        long ob = (((long)b * NKV_ + (ct - NH_)) * S_ + s) * HD_;
                        Kr[ob + i]      = __float2bfloat16(o1);
                        Kr[ob + i + 64] = __float2bfloat16(o2);
                    }
                }
            }
        }
    } else {
        // V heads: bias + direct sigma-transposed store to VtG[b][j][sigma(s)]
        const int qswap = ((quad & 1) << 1) | ((quad >> 1) & 1);
#pragma unroll
        for (int mi = 0; mi < 4; mi++) {
            long rbase = row0 + wr * 64 + mi * 16;    // 16-aligned
            int bb  = (int)(rbase >> 11);
            int s16 = (int)(rbase & 2047);
#pragma unroll
            for (int ni = 0; ni < 4; ni++) {
                int c = wc * 64 + ni * 16 + l16;
                int j = (ct - 18) * 128 + c;
                float bv = bias[ct * 128 + c];
                bf16 o[4];
#pragma unroll
                for (int reg = 0; reg < 4; reg++)
                    o[reg] = __float2bfloat16(acc[mi][ni][reg] + bv);
                *(ulong1*)(VtG + ((long)(bb * 256 + j)) * S_ + s16 + qswap * 4) =
                    *(ulong1*)o;
            }
        }
    }
}

// ---------------------------------------------------------------------------
// Output projection GEMM: 128x128 tile, BK=64, fp32 out. T1 swizzle (512=8*64).
__global__ __launch_bounds__(256, 3) void gemm_out(
    const bf16* __restrict__ A, const bf16* __restrict__ Bt,
    float* __restrict__ Cout, int M, int N, int K)
{
    __shared__ __align__(16) bf16 As[128 * 64];
    __shared__ __align__(16) bf16 Bs[128 * 64];
    const int tid = threadIdx.x;
    const int wave = tid >> 6, lane = tid & 63;
    const int quad = lane >> 4, l16 = lane & 15;
    const int wr = wave >> 1, wc = wave & 1;

    // T1 XCD swizzle: bijective since nwg % 8 == 0
    const int nwg  = gridDim.x * gridDim.y;
    const int orig = blockIdx.y * gridDim.x + blockIdx.x;
    const int swz  = (orig & 7) * (nwg >> 3) + (orig >> 3);
    const int bx = swz % gridDim.x, by = swz / gridDim.x;

    const long row0 = (long)by * 128;
    const long col0 = (long)bx * 128;

    f32x4 acc[4][4];
#pragma unroll
    for (int i = 0; i < 4; i++)
#pragma unroll
        for (int j = 0; j < 4; j++) acc[i][j] = {0.f, 0.f, 0.f, 0.f};

    for (int k0 = 0; k0 < K; k0 += 64) {
        __syncthreads();
#pragma unroll
        for (int i = 0; i < 4; i++) {
            int cb = i * 256 + wave * 64;
            int c = cb + lane;
            int r = c >> 3, sc = c & 7;
            int gc = sc ^ (r & 7);
            async_load16(A + (row0 + r) * K + k0 + gc * 8, As + (size_t)cb * 8);
            async_load16(Bt + (col0 + r) * K + k0 + gc * 8, Bs + (size_t)cb * 8);
        }
        __syncthreads();

#pragma unroll
        for (int ks2 = 0; ks2 < 2; ks2++) {
            const int slot = ((ks2 * 4 + quad) ^ (l16 & 7)) * 8;
            bf16x8 af[4], bfr[4];
#pragma unroll
            for (int mi = 0; mi < 4; mi++)
                af[mi] = *(const bf16x8*)(As + (wr * 64 + mi * 16 + l16) * 64 + slot);
#pragma unroll
            for (int ni = 0; ni < 4; ni++)
                bfr[ni] = *(const bf16x8*)(Bs + (wc * 64 + ni * 16 + l16) * 64 + slot);
#pragma unroll
            for (int mi = 0; mi < 4; mi++)
#pragma unroll
                for (int ni = 0; ni < 4; ni++)
                    acc[mi][ni] = __builtin_amdgcn_mfma_f32_16x16x32_bf16(
                        af[mi], bfr[ni], acc[mi][ni], 0, 0, 0);
        }
    }

#pragma unroll
    for (int mi = 0; mi < 4; mi++) {
        long r = row0 + wr * 64 + mi * 16 + quad * 4;
#pragma unroll
        for (int ni = 0; ni < 4; ni++) {
            long c = col0 + wc * 64 + ni * 16 + l16;
#pragma unroll
            for (int reg = 0; reg < 4; reg++)
                Cout[(r + reg) * N + c] = acc[mi][ni][reg];
        }
    }
}

// ---------------------------------------------------------------------------
// Causal GQA flash attention, 32x32x16 MFMA, 128q x 64k tiles, 4 waves.
// R7 = verified R5 structure: 64KB LDS (K+V double-buffered), single barrier
// per kt, launch_bounds(256,2) -- register demand ~200 unified regs means
// max 2 waves/SIMD (512-reg pool/SIMD); (256,3) spilled to scratch (R6,
// 2.7x regression). Fused dual-subtile compute (ILP=2 QK chains, mask
// specialization, split lsum). No setprio (measured regression, R4).
__global__ __launch_bounds__(256, 2) void attn_kernel(
    const bf16* __restrict__ Q,   // [B][NH][S][HD], pre-scaled by SCALE*log2e
    const bf16* __restrict__ Kk,  // [B][NKV][S][HD]
    const bf16* __restrict__ Vt,  // [B][NKV*HD][sigma(S)]
    bf16* __restrict__ O)         // [B][S][NH*HD]
{
    const int id = blockIdx.x;
    const int hb = id & 31;
    const int h = hb & 15, b = hb >> 4;
    const int q4 = (id >> 5) & 7, hi = id >> 8;
    const int qtile = hi ? (15 - q4) : q4;    // co-resident pair sums to 15
    const int kvh = h >> 3;
    const int tid = threadIdx.x, wave = tid >> 6, lane = tid & 63;
    const int l31 = lane & 31, half = lane >> 5;
    const int qh = wave;                      // q rows qh*32..+31

    __shared__ __align__(16) char smem[64 * 1024];
    __shared__ float Ls[128];

    const bf16* Kbase = Kk + ((long)(b * NKV_ + kvh) * S_) * HD_;
    const bf16* Vbase = Vt + ((long)b * (2 * HD_) + kvh * HD_) * (long)S_;

    // stage all 128 Q rows (32 KB across both halves of buf0), hoist B-frags
    const bf16* Qg = Q + (((long)(b * NH_ + h) * S_) + qtile * 128) * HD_;
    bf16* Qs = (bf16*)smem;
#pragma unroll
    for (int i = 0; i < 8; i++) {
        int cb = i * 256 + wave * 64;
        int c = cb + lane, r = c >> 4, sc = c & 15;
        async_load16(Qg + r * HD_ + (sc ^ (r & 15)) * 8, Qs + (size_t)cb * 8);
    }
    __syncthreads();
    bf16x8 qf[8];
#pragma unroll
    for (int ks = 0; ks < 8; ks++) {
        int gc = 2 * ks + half;
        qf[ks] = *(const bf16x8*)(Qs + (qh * 32 + l31) * 128 +
                                  ((gc ^ (l31 & 15)) * 8));
    }
    __syncthreads();   // smem now reusable for K/V tiles

    f32x16 acc_o[4];
#pragma unroll
    for (int r = 0; r < 16; r++) {
        acc_o[0][r] = 0.f; acc_o[1][r] = 0.f;
        acc_o[2][r] = 0.f; acc_o[3][r] = 0.f;
    }
    float lsum0 = 0.f, lsum1 = 0.f;

    const int qc32 = qtile * 4 + qh;          // this wave's 32-q chunk index
    const int kt_max = 2 * qtile + 1;

    // prologue: issue kt=0 into buf 0
    {
        bf16* KsW  = (bf16*)smem;
        bf16* VtsW = (bf16*)(smem + 16384);
#pragma unroll
        for (int i = 0; i < 4; i++) {
            int cb = i * 256 + wave * 64;
            int c = cb + lane, r = c >> 4, sc = c & 15;
            async_load16(Kbase + r * HD_ + (sc ^ (r & 15)) * 8,
                         KsW + (size_t)cb * 8);
        }
#pragma unroll
        for (int i = 0; i < 4; i++) {
            int cb = i * 256 + wave * 64;
            int c = cb + lane, r = c >> 3, sc = c & 7;
            async_load16(Vbase + (long)r * S_ + (sc ^ (r & 7)) * 8,
                         VtsW + (size_t)cb * 8);
        }
    }

#pragma unroll 1
    for (int kt = 0; kt <= kt_max; kt++) {
        __syncthreads();   // buf[kt&1] complete; prev compute done everywhere
        const bf16* Ks  = (const bf16*)(smem + (kt & 1) * 32768);
        const bf16* Vts = (const bf16*)(smem + (kt & 1) * 32768 + 16384);

        if (kt < kt_max) {   // prefetch kt+1 into the other buffer
            bf16* KsW  = (bf16*)(smem + ((kt + 1) & 1) * 32768);
            bf16* VtsW = (bf16*)(smem + ((kt + 1) & 1) * 32768 + 16384);
            const bf16* Kg = Kbase + (long)(kt + 1) * 64 * HD_;
#pragma unroll
            for (int i = 0; i < 4; i++) {
                int cb = i * 256 + wave * 64;
                int c = cb + lane, r = c >> 4, sc = c & 15;
                async_load16(Kg + r * HD_ + (sc ^ (r & 15)) * 8,
                             KsW + (size_t)cb * 8);
            }
            const bf16* Vg = Vbase + (kt + 1) * 64;
#pragma unroll
            for (int i = 0; i < 4; i++) {
                int cb = i * 256 + wave * 64;
                int c = cb + lane, r = c >> 3, sc = c & 7;
                async_load16(Vg + (long)r * S_ + (sc ^ (r & 7)) * 8,
                             VtsW + (size_t)cb * 8);
            }
        }

        // --- fused dual-subtile compute -----------------------------------
        auto qk = [&](int mh, f32x16& st) {
#pragma unroll
            for (int ks = 0; ks < 8; ks++) {
                int gc = 2 * ks + half;
                bf16x8 ka = *(const bf16x8*)(Ks + (mh * 32 + l31) * 128 +
                                             ((gc ^ (l31 & 15)) * 8));
                st = __builtin_amdgcn_mfma_f32_32x32x16_bf16(ka, qf[ks], st,
                                                             0, 0, 0);
            }
        };
        auto smax = [&](const f32x16& st, bool tri, bf16x8 (&pa)[2],
                        float& ls) {
#pragma unroll
            for (int t = 0; t < 2; t++)
#pragma unroll
                for (int j = 0; j < 8; j++) {
                    int r = t * 8 + j;
                    int krow = (r & 3) + 8 * (r >> 2) + 4 * half;
                    float x = st[r];
                    if (tri && krow > l31) x = -1e30f;
                    float pv = __builtin_amdgcn_exp2f(x);
                    ls += pv;                 // lane l31 = q here
                    pa[t][j] = f2bf(pv);
                }
        };
        auto pv_acc = [&](int mh, bf16x8 (&pa)[2]) {
#pragma unroll
            for (int t = 0; t < 2; t++) {
                int gc = 4 * mh + 2 * t + half;
#pragma unroll
                for (int nt = 0; nt < 4; nt++) {
                    bf16x8 vb = *(const bf16x8*)(Vts + (nt * 32 + l31) * 64 +
                                                 ((gc ^ (l31 & 7)) * 8));
                    acc_o[nt] = __builtin_amdgcn_mfma_f32_32x32x16_bf16(
                        pa[t], vb, acc_o[nt], 0, 0, 0);
                }
            }
        };

        const int kc0 = 2 * kt, kc1 = 2 * kt + 1;
        if (kc1 <= qc32) {
            // both subtiles live; subtile0 provably unmasked (kc0 < qc32)
            f32x16 st0, st1;
#pragma unroll
            for (int r = 0; r < 16; r++) { st0[r] = 0.f; st1[r] = 0.f; }
            qk(0, st0);
            qk(1, st1);
            bf16x8 pa0[2], pa1[2];
            smax(st0, false, pa0, lsum0);
            smax(st1, kc1 == qc32, pa1, lsum1);
            pv_acc(0, pa0);
            pv_acc(1, pa1);
        } else if (kc0 <= qc32) {
            // single subtile; provably triangular (kc0 == qc32)
            f32x16 st0;
#pragma unroll
            for (int r = 0; r < 16; r++) st0[r] = 0.f;
            qk(0, st0);
            bf16x8 pa0[2];
            smax(st0, true, pa0, lsum0);
            pv_acc(0, pa0);
        }
    }

    // row-sum broadcast: lsum indexed by lane=q; acc_o rows are reg-indexed q.
    float lsum = lsum0 + lsum1;
    float ltot = lsum + __shfl_xor(lsum, 32);
    __syncthreads();   // all compute done before Ls write
    if (half == 0) Ls[qh * 32 + l31] = ltot;
    __syncthreads();

    float inv_l[16];
#pragma unroll
    for (int r = 0; r < 16; r++) {
        int qrow = (r & 3) + 8 * (r >> 2) + 4 * half;
        inv_l[r] = __builtin_amdgcn_rcpf(Ls[qh * 32 + qrow]);
    }
#pragma unroll
    for (int nt = 0; nt < 4; nt++)
#pragma unroll
        for (int r = 0; r < 16; r++) {
            int qrow = (r & 3) + 8 * (r >> 2) + 4 * half;
            float v = acc_o[nt][r] * inv_l[r];
            O[((long)b * S_ + qtile * 128 + qh * 32 + qrow) * (NH_ * HD_) +
              h * HD_ + nt * 32 + l31] = __float2bfloat16(v);
        }
}

// ---------------------------------------------------------------------------
extern "C" void kernel_launch(void* const* d_in, const int* in_sizes, int n_in,
                              void* d_out, int out_size, void* d_ws, size_t ws_size,
                              hipStream_t stream) {
    const int*   pos  = (const int*)d_in[0];
    const float* X    = (const float*)d_in[1];
    const float* Wqkv = (const float*)d_in[2];
    const float* bqkv = (const float*)d_in[3];
    const float* Wo   = (const float*)d_in[4];
    float* out = (float*)d_out;

    char* ws = (char*)d_ws;
    bf16* Xb    = (bf16*)ws;  ws += (size_t)B_ * S_ * HID_ * 2;
    bf16* Wqkvt = (bf16*)ws;  ws += (size_t)QKV_N * HID_ * 2;
    bf16* Wot   = (bf16*)ws;  ws += (size_t)HID_ * HID_ * 2;
    bf16* Qr    = (bf16*)ws;  ws += (size_t)B_ * NH_ * S_ * HD_ * 2;
    bf16* Kr    = (bf16*)ws;  ws += (size_t)B_ * NKV_ * S_ * HD_ * 2;
    bf16* VtG   = (bf16*)ws;  ws += (size_t)B_ * NKV_ * HD_ * S_ * 2;
    bf16* AO    = (bf16*)ws;  ws += (size_t)B_ * S_ * NH_ * HD_ * 2;

    // 1. fused cast + weight transposes (Wqkvt phi-permuted)
    prep1<<<17408, 256, 0, stream>>>(X, Xb, Wqkv, Wqkvt, Wo, Wot);

    // 2. QKV projection + bias + RoPE + direct sigma'd V write (T1 swizzle)
    gemm_qkv<<<dim3(QKV_N / 128, (B_ * S_) / 128), 256, 0, stream>>>(
        Xb, Wqkvt, bqkv, pos, Qr, Kr, VtG);

    // 3. causal GQA attention (512 blocks, 2 blocks/CU, 64KB LDS)
    attn_kernel<<<dim3(512), 256, 0, stream>>>(Qr, Kr, VtG, AO);

    // 4. output projection (512 blocks, T1 swizzle, fp32 out)
    gemm_out<<<dim3(HID_ / 128, (B_ * S_) / 128), 256, 0, stream>>>(
        AO, Wot, out, B_ * S_, HID_, HID_);
}